// Round 8
// baseline (301.790 us; speedup 1.0000x reference)
//
#include <hip/hip_runtime.h>
#include <stdint.h>

// Problem constants (B,N,D,H fixed by setup_inputs)
#define B_  8
#define N_  768
#define D_  2048
#define H_  4
#define HN  192   // head width n = N/H

// padded global/LDS layouts for attention (conflict-free DMA-linear)
#define QROW 200          // K/Q row: 192 + 8 pad u16  -> 400 B (≡4 banks)
#define VROW 72           // V row: 64 + 8 pad u16     -> 144 B (≡4 banks)
#define KTILE_B 25600     // 64 * 400 B  (25 x 1024)
#define VTILE_B 27648     // 192 * 144 B (27 x 1024)

#define LOG2E 1.4426950408889634f
#define C2    2.8853901617f      // 2*log2e

typedef unsigned short u16;
typedef float    f32x4 __attribute__((ext_vector_type(4)));
typedef __bf16   bf16x8 __attribute__((ext_vector_type(8)));
typedef __bf16   bf16x4 __attribute__((ext_vector_type(4)));
typedef uint32_t u32x4 __attribute__((ext_vector_type(4)));
typedef uint32_t u32x2 __attribute__((ext_vector_type(2)));

// native bf16 convert: compiler pairs these into v_cvt_pk_bf16_f32 (RNE)
__device__ __forceinline__ u16 f2bf(float f) {
  return __builtin_bit_cast(u16, (__bf16)f);
}

// async global->LDS DMA, 16 B per lane; LDS dest = uniform base + lane*16
typedef const __attribute__((address_space(1))) void* gas_ptr;
typedef __attribute__((address_space(3))) void* las_ptr;
__device__ __forceinline__ void gld16(const void* g, void* l) {
  __builtin_amdgcn_global_load_lds((gas_ptr)g, (las_ptr)l, 16, 0, 0);
}

// ---------------------------------------------------------------------------
// Kernel 0: fused prep. Flat grid of 4864 blocks:
//   [0,3072)    transpose x (B,N,D) fp32 -> xt (B,D,N) bf16
//   [3072,4800) convert the three weight matrices fp32 -> bf16 (576 blk each)
//   [4800,4864) zero the q2 accumulator (ws is poisoned 0xAA each launch)
// ---------------------------------------------------------------------------
__global__ __launch_bounds__(256) void prep(const float* __restrict__ x,
                                            const float* __restrict__ Wqk,
                                            const float* __restrict__ Wv,
                                            const float* __restrict__ Wout,
                                            u16* __restrict__ xt,
                                            u16* __restrict__ oqk,
                                            u16* __restrict__ ov,
                                            u16* __restrict__ oout,
                                            float* __restrict__ q2) {
  __shared__ float tile[64][65];
  const int bid = blockIdx.x;
  const int t   = threadIdx.x;
  if (bid < 3072) {
    const int d0 = (bid & 31) * 64;
    const int n0 = ((bid >> 5) % 12) * 64;
    const int b  = (bid >> 5) / 12;
    const int col = t & 63;
    const int rb  = (t >> 6) * 16;
    const float* src = x + ((size_t)b * N_ + n0) * D_ + d0;
    #pragma unroll
    for (int i = 0; i < 16; i++)
      tile[rb + i][col] = src[(size_t)(rb + i) * D_ + col];
    __syncthreads();
    u16* dst = xt + ((size_t)b * D_ + d0) * N_ + n0;
    #pragma unroll
    for (int i = 0; i < 16; i++)
      dst[(size_t)(rb + i) * N_ + col] = f2bf(tile[col][rb + i]);
  } else if (bid < 4800) {
    const int r   = bid - 3072;         // 0..1727
    const int mat = r / 576;            // 576 blocks per matrix (N*N/1024)
    const float* src = (mat == 0) ? Wqk : ((mat == 1) ? Wv : Wout);
    u16*         dst = (mat == 0) ? oqk : ((mat == 1) ? ov : oout);
    const int i = ((r % 576) * 256 + t) * 4;
    f32x4 v = *(const f32x4*)(src + i);
    bf16x4 tmp;
    #pragma unroll
    for (int j = 0; j < 4; j++) tmp[j] = (__bf16)v[j];
    *(bf16x4*)(dst + i) = tmp;
  } else {
    const f32x4 fz = {0.f, 0.f, 0.f, 0.f};
    const int i = ((bid - 4800) * 256 + t) * 4;
    *(f32x4*)(q2 + i) = fz;
  }
}

// ---------------------------------------------------------------------------
// Kernels 1a/1b/3 share the 256x192 / 8-wave / BK=32 / dbuf skeleton:
//   grid (D/256, N/192, B) = 256 blocks = exactly 1 block/CU.
//   192-wide j tile == one head (HN=192): no head straddling anywhere.
//   waves 2(wm) x 4(wn): each wave owns 128 d x 48 j = 8(mi) x 3(nj) frags
//   -> 96-VGPR accumulator (the fused qkv dual-acc would spill; split).
//   Staging: dbuf LDS, A 2x16KB + B 2x12KB = 56 KB; STAGE(t+1) issued
//   before compute(t).  At 256x192 the compute phase (~1870 cy) exceeds
//   staging BW cost (~700 cy) -> compute-bound (128^2 was L2-BW-bound).
// ---------------------------------------------------------------------------

// ---- Kernel 1a: qk GEMM (swapped mfma(Bq,A) -> jn-consecutive lanes) ------
__global__ __launch_bounds__(512, 2) void qk_gemm(const u16* __restrict__ xt,
                                                  const u16* __restrict__ wqk,
                                                  u16* __restrict__ qkb,
                                                  float* __restrict__ q2) {
  const int b  = blockIdx.z;
  const int d0 = blockIdx.x * 256;
  const int h  = blockIdx.y;           // j tile == head
  const int j0 = h * HN;
  const int tid  = threadIdx.x;
  const int wave = tid >> 6, lane = tid & 63;
  const int l15  = lane & 15, quad = lane >> 4;
  const int wm = wave >> 2, wn = wave & 3;

  __shared__ u16 At[2][256 * 32];   // 2 x 16 KB
  __shared__ u16 Bt[2][192 * 32];   // 2 x 12 KB

  const f32x4 fz = {0.f, 0.f, 0.f, 0.f};
  f32x4 acc[3][8];   // [nj][mi]  C^T layout: row=j, col=d
  #pragma unroll
  for (int i = 0; i < 3; i++)
    #pragma unroll
    for (int j = 0; j < 8; j++) acc[i][j] = fz;

  const int srow  = tid >> 2;          // 0..127
  const int sbyte = (tid & 3) * 16;
  const u16* ax = xt  + ((size_t)b * D_ + d0 + srow) * N_;
  const u16* bq = wqk + (size_t)(j0 + srow) * N_;

  #define KSTG(BUF, K0)                                                       \
    { gld16((const char*)(ax + (K0)) + sbyte, (char*)At[BUF] + tid * 16);     \
      gld16((const char*)(ax + (size_t)128 * N_ + (K0)) + sbyte,              \
            (char*)At[BUF] + 8192 + tid * 16);                                \
      gld16((const char*)(bq + (K0)) + sbyte, (char*)Bt[BUF] + tid * 16);     \
      if (tid < 256)                                                          \
        gld16((const char*)(bq + (size_t)128 * N_ + (K0)) + sbyte,            \
              (char*)Bt[BUF] + 8192 + tid * 16); }

  KSTG(0, 0);

  for (int t = 0; t < 24; t++) {
    __syncthreads();
    if (t < 23) KSTG((t + 1) & 1, (t + 1) * 32);
    const u16* at = At[t & 1];
    const u16* bt = Bt[t & 1];

    bf16x8 Af[8];
    #pragma unroll
    for (int mi = 0; mi < 8; mi++)
      Af[mi] = *(const bf16x8*)&at[(wm * 128 + mi * 16 + l15) * 32 + quad * 8];
    #pragma unroll
    for (int nj = 0; nj < 3; nj++) {
      bf16x8 Bf = *(const bf16x8*)&bt[(wn * 48 + nj * 16 + l15) * 32 + quad * 8];
      #pragma unroll
      for (int mi = 0; mi < 8; mi++)
        acc[nj][mi] = __builtin_amdgcn_mfma_f32_16x16x32_bf16(Bf, Af[mi], acc[nj][mi], 0, 0, 0);
    }
  }

  const size_t bh = (size_t)b * H_ + h;

  // q2 partial sums (lane owns d = col; this wave covers 48 of the 192 jn)
  #pragma unroll
  for (int md = 0; md < 8; md++) {
    float s = 0.f;
    #pragma unroll
    for (int nj = 0; nj < 3; nj++)
      #pragma unroll
      for (int r = 0; r < 4; r++) { float v = acc[nj][md][r]; s += v * v; }
    s += __shfl_xor(s, 16, 64);
    s += __shfl_xor(s, 32, 64);
    if (quad == 0)
      atomicAdd(&q2[bh * D_ + d0 + wm * 128 + md * 16 + l15], s * LOG2E);
  }

  // direct store: lane holds 4 jn-consecutive values per fragment
  u16* qtbase = qkb + bh * (size_t)(D_ * QROW);
  #pragma unroll
  for (int md = 0; md < 8; md++) {
    const size_t dro = (size_t)(d0 + wm * 128 + md * 16 + l15) * QROW;
    #pragma unroll
    for (int nj = 0; nj < 3; nj++) {
      bf16x4 tmp;
      #pragma unroll
      for (int r = 0; r < 4; r++) tmp[r] = (__bf16)acc[nj][md][r];
      *(bf16x4*)(qtbase + dro + wn * 48 + nj * 16 + quad * 4) = tmp;
    }
  }
}

// ---- Kernel 1b: v GEMM (normal mfma(A,Bv) -> e-consecutive lanes) ---------
__global__ __launch_bounds__(512, 2) void v_gemm(const u16* __restrict__ xt,
                                                 const u16* __restrict__ wv,
                                                 u16* __restrict__ vtb) {
  const int b  = blockIdx.z;
  const int dtile = blockIdx.x;        // 256-wide e tile
  const int d0 = dtile * 256;
  const int h  = blockIdx.y;
  const int j0 = h * HN;
  const int tid  = threadIdx.x;
  const int wave = tid >> 6, lane = tid & 63;
  const int l15  = lane & 15, quad = lane >> 4;
  const int wm = wave >> 2, wn = wave & 3;

  __shared__ u16 At[2][256 * 32];
  __shared__ u16 Bt[2][192 * 32];

  const f32x4 fz = {0.f, 0.f, 0.f, 0.f};
  f32x4 acc[8][3];   // [mi][ni]  C layout: row=d(=e), col=j
  #pragma unroll
  for (int i = 0; i < 8; i++)
    #pragma unroll
    for (int j = 0; j < 3; j++) acc[i][j] = fz;

  const int srow  = tid >> 2;
  const int sbyte = (tid & 3) * 16;
  const u16* ax = xt + ((size_t)b * D_ + d0 + srow) * N_;
  const u16* bv = wv + (size_t)(j0 + srow) * N_;

  #define VSTG(BUF, K0)                                                       \
    { gld16((const char*)(ax + (K0)) + sbyte, (char*)At[BUF] + tid * 16);     \
      gld16((const char*)(ax + (size_t)128 * N_ + (K0)) + sbyte,              \
            (char*)At[BUF] + 8192 + tid * 16);                                \
      gld16((const char*)(bv + (K0)) + sbyte, (char*)Bt[BUF] + tid * 16);     \
      if (tid < 256)                                                          \
        gld16((const char*)(bv + (size_t)128 * N_ + (K0)) + sbyte,            \
              (char*)Bt[BUF] + 8192 + tid * 16); }

  VSTG(0, 0);

  for (int t = 0; t < 24; t++) {
    __syncthreads();
    if (t < 23) VSTG((t + 1) & 1, (t + 1) * 32);
    const u16* at = At[t & 1];
    const u16* bt = Bt[t & 1];

    bf16x8 Af[8];
    #pragma unroll
    for (int mi = 0; mi < 8; mi++)
      Af[mi] = *(const bf16x8*)&at[(wm * 128 + mi * 16 + l15) * 32 + quad * 8];
    #pragma unroll
    for (int ni = 0; ni < 3; ni++) {
      bf16x8 Bf = *(const bf16x8*)&bt[(wn * 48 + ni * 16 + l15) * 32 + quad * 8];
      #pragma unroll
      for (int mi = 0; mi < 8; mi++)
        acc[mi][ni] = __builtin_amdgcn_mfma_f32_16x16x32_bf16(Af[mi], Bf, acc[mi][ni], 0, 0, 0);
    }
  }

  const size_t bh = (size_t)b * H_ + h;
  // direct store: lane holds 4 e-consecutive values per fragment
  u16* vtbase = vtb + bh * (size_t)(32 * HN * VROW);
  #pragma unroll
  for (int mi = 0; mi < 8; mi++) {
    const int etile = dtile * 4 + wm * 2 + (mi >> 2);   // 64-wide e tile
    const int el    = (mi & 3) * 16 + quad * 4;          // e-local
    u16* base = vtbase + (size_t)etile * (HN * VROW);
    #pragma unroll
    for (int ni = 0; ni < 3; ni++) {
      bf16x4 tmp;
      #pragma unroll
      for (int r = 0; r < 4; r++) tmp[r] = (__bf16)acc[mi][ni][r];
      *(bf16x4*)(base + (size_t)(wn * 48 + ni * 16 + l15) * VROW + el) = tmp;
    }
  }
}

// ---------------------------------------------------------------------------
// Kernel 2: fused attention v5 (verified best, 122 us — restored exactly).
//   S^T = K·Q^T trick; exp2 path with pre-scaled q2; MFMA ones-rowsum;
//   setprio around MFMA clusters.  4 waves x 32 d-rows; grid 512, 2 blk/CU.
// ---------------------------------------------------------------------------
__global__ __launch_bounds__(256, 2) void attn_kernel(const u16* __restrict__ qkb,
                                                      const u16* __restrict__ vtb,
                                                      const float* __restrict__ q2,
                                                      u16* __restrict__ wbuf) {
  const int bid  = blockIdx.x;
  const int bh   = (bid & 7) * 4 + (bid >> 7);  // xcd*4 + sub: 4 bh per XCD
  const int dblk = (bid >> 3) & 15;             // 128-row block
  const int b = bh >> 2, h = bh & 3;
  const int tid  = threadIdx.x;
  const int wave = tid >> 6, lane = tid & 63;
  const int l15  = lane & 15, quad = lane >> 4;

  __shared__ u16 Klds[64 * QROW];        // 25.6 KB  [e][200]
  __shared__ u16 Vlds[HN * VROW];        // 27.6 KB  [jn][72]
  __shared__ u16 Plds[4][32][VROW];      // 18.4 KB  per-wave P [d][e(64)+pad]

  const u16* kg = qkb + (size_t)bh * (D_ * QROW);
  const u16* vg = vtb + (size_t)bh * (32 * HN * VROW);
  const float* q2g = q2 + (size_t)bh * D_;

  bf16x8 Qf[2][6];
  {
    const u16* qrow = kg + (size_t)(dblk * 128 + wave * 32 + l15) * QROW + quad * 8;
    #pragma unroll
    for (int nt = 0; nt < 2; nt++)
      #pragma unroll
      for (int f = 0; f < 6; f++)
        Qf[nt][f] = *(const bf16x8*)(qrow + (size_t)nt * 16 * QROW + f * 32);
  }
  float cd[2];
  cd[0] = q2g[dblk * 128 + wave * 32 + l15];
  cd[1] = q2g[dblk * 128 + wave * 32 + 16 + l15];

  bf16x8 OnesF;
  #pragma unroll
  for (int j = 0; j < 8; j++) OnesF[j] = (__bf16)1.0f;

  const f32x4 fz = {0.f, 0.f, 0.f, 0.f};
  f32x4 O[2][12];
  f32x4 Or[2];
  #pragma unroll
  for (int mt = 0; mt < 2; mt++) {
    Or[mt] = fz;
    #pragma unroll
    for (int c = 0; c < 12; c++) O[mt][c] = fz;
  }

  for (int t = 0; t < 32; t++) {
    __syncthreads();   // all waves done reading previous K/V
    {
      const char* ks = (const char*)kg + (size_t)t * KTILE_B;
      char* kd = (char*)Klds;
      for (int c = wave; c < 25; c += 4)
        gld16(ks + c * 1024 + lane * 16, kd + c * 1024 + lane * 16);
      const char* vs = (const char*)vg + (size_t)t * VTILE_B;
      char* vd = (char*)Vlds;
      for (int c = wave; c < 27; c += 4)
        gld16(vs + c * 1024 + lane * 16, vd + c * 1024 + lane * 16);
    }
    __syncthreads();   // barrier's vmcnt(0) drains the DMA

    #pragma unroll
    for (int et = 0; et < 4; et++) {
      bf16x8 Kf[6];
      #pragma unroll
      for (int f = 0; f < 6; f++)
        Kf[f] = *(const bf16x8*)&Klds[(et * 16 + l15) * QROW + f * 32 + quad * 8];
      f32x4 S0 = fz, S1 = fz;
      __builtin_amdgcn_s_setprio(1);
      #pragma unroll
      for (int f = 0; f < 6; f++) {
        S0 = __builtin_amdgcn_mfma_f32_16x16x32_bf16(Kf[f], Qf[0][f], S0, 0, 0, 0);
        S1 = __builtin_amdgcn_mfma_f32_16x16x32_bf16(Kf[f], Qf[1][f], S1, 0, 0, 0);
      }
      __builtin_amdgcn_s_setprio(0);
      const f32x4 ce = *(const f32x4*)&q2g[t * 64 + et * 16 + quad * 4];
      bf16x4 pb0, pb1;
      #pragma unroll
      for (int r = 0; r < 4; r++) {
        float p0 = __builtin_amdgcn_exp2f(__builtin_fmaf(S0[r], C2, -(ce[r] + cd[0])));
        float p1 = __builtin_amdgcn_exp2f(__builtin_fmaf(S1[r], C2, -(ce[r] + cd[1])));
        pb0[r] = (__bf16)p0;
        pb1[r] = (__bf16)p1;
      }
      *(bf16x4*)&Plds[wave][l15][et * 16 + quad * 4]      = pb0;
      *(bf16x4*)&Plds[wave][16 + l15][et * 16 + quad * 4] = pb1;
    }

    #pragma unroll
    for (int kk = 0; kk < 2; kk++) {
      bf16x8 Pf0 = *(const bf16x8*)&Plds[wave][l15][kk * 32 + quad * 8];
      bf16x8 Pf1 = *(const bf16x8*)&Plds[wave][16 + l15][kk * 32 + quad * 8];
      __builtin_amdgcn_s_setprio(1);
      #pragma unroll
      for (int c = 0; c < 12; c++) {
        bf16x8 Vf = *(const bf16x8*)&Vlds[(c * 16 + l15) * VROW + kk * 32 + quad * 8];
        O[0][c] = __builtin_amdgcn_mfma_f32_16x16x32_bf16(Pf0, Vf, O[0][c], 0, 0, 0);
        O[1][c] = __builtin_amdgcn_mfma_f32_16x16x32_bf16(Pf1, Vf, O[1][c], 0, 0, 0);
      }
      Or[0] = __builtin_amdgcn_mfma_f32_16x16x32_bf16(Pf0, OnesF, Or[0], 0, 0, 0);
      Or[1] = __builtin_amdgcn_mfma_f32_16x16x32_bf16(Pf1, OnesF, Or[1], 0, 0, 0);
      __builtin_amdgcn_s_setprio(0);
    }
  }

  #pragma unroll
  for (int mt = 0; mt < 2; mt++)
    #pragma unroll
    for (int r = 0; r < 4; r++) {
      const float inv = __builtin_amdgcn_rcpf(Or[mt][r]);
      const int d = dblk * 128 + wave * 32 + mt * 16 + quad * 4 + r;
      u16* wrow = wbuf + ((size_t)b * D_ + d) * N_ + h * HN;
      #pragma unroll
      for (int c = 0; c < 12; c++)
        wrow[c * 16 + l15] = f2bf(O[mt][c][r] * inv);
    }
}

// ---- Kernel 3: out GEMM, 256x192 skeleton --------------------------------
__global__ __launch_bounds__(512, 2) void out_gemm(const u16* __restrict__ wbuf,
                                                   const u16* __restrict__ wout,
                                                   float* __restrict__ outp) {
  const int b  = blockIdx.z;
  const int d0 = blockIdx.x * 256;
  const int i0 = blockIdx.y * 192;
  const int tid  = threadIdx.x;
  const int wave = tid >> 6, lane = tid & 63;
  const int l15  = lane & 15, quad = lane >> 4;
  const int wm = wave >> 2, wn = wave & 3;

  __shared__ u16 At[2][256 * 32];
  __shared__ u16 Bt[2][192 * 32];

  const f32x4 fz = {0.f, 0.f, 0.f, 0.f};
  f32x4 acc[8][3];   // [mi][ni]  C layout: row=d, col=i
  #pragma unroll
  for (int i = 0; i < 8; i++)
    #pragma unroll
    for (int j = 0; j < 3; j++) acc[i][j] = fz;

  const int srow  = tid >> 2;
  const int sbyte = (tid & 3) * 16;
  const u16* ax = wbuf + ((size_t)b * D_ + d0 + srow) * N_;
  const u16* bw = wout + (size_t)(i0 + srow) * N_;

  #define OSTG(BUF, K0)                                                       \
    { gld16((const char*)(ax + (K0)) + sbyte, (char*)At[BUF] + tid * 16);     \
      gld16((const char*)(ax + (size_t)128 * N_ + (K0)) + sbyte,              \
            (char*)At[BUF] + 8192 + tid * 16);                                \
      gld16((const char*)(bw + (K0)) + sbyte, (char*)Bt[BUF] + tid * 16);     \
      if (tid < 256)                                                          \
        gld16((const char*)(bw + (size_t)128 * N_ + (K0)) + sbyte,            \
              (char*)Bt[BUF] + 8192 + tid * 16); }

  OSTG(0, 0);

  for (int t = 0; t < 24; t++) {
    __syncthreads();
    if (t < 23) OSTG((t + 1) & 1, (t + 1) * 32);
    const u16* at = At[t & 1];
    const u16* bt = Bt[t & 1];

    bf16x8 Af[8];
    #pragma unroll
    for (int mi = 0; mi < 8; mi++)
      Af[mi] = *(const bf16x8*)&at[(wm * 128 + mi * 16 + l15) * 32 + quad * 8];
    #pragma unroll
    for (int ni = 0; ni < 3; ni++) {
      bf16x8 Bf = *(const bf16x8*)&bt[(wn * 48 + ni * 16 + l15) * 32 + quad * 8];
      #pragma unroll
      for (int mi = 0; mi < 8; mi++)
        acc[mi][ni] = __builtin_amdgcn_mfma_f32_16x16x32_bf16(Af[mi], Bf, acc[mi][ni], 0, 0, 0);
    }
  }

  // direct store: f32x4 per fragment (d-consecutive for fixed i)
  #pragma unroll
  for (int ni = 0; ni < 3; ni++) {
    float* orow = outp + ((size_t)b * N_ + i0 + wn * 48 + ni * 16 + l15) * D_
                + d0 + wm * 128 + quad * 4;
    #pragma unroll
    for (int mi = 0; mi < 8; mi++)
      *(f32x4*)(orow + mi * 16) = acc[mi][ni];
  }
}

// ---------------------------------------------------------------------------
extern "C" void kernel_launch(void* const* d_in, const int* in_sizes, int n_in,
                              void* d_out, int out_size, void* d_ws, size_t ws_size,
                              hipStream_t stream) {
  (void)in_sizes; (void)n_in; (void)out_size; (void)ws_size;
  const float* x    = (const float*)d_in[0];
  const float* Wqk  = (const float*)d_in[1];
  const float* Wv   = (const float*)d_in[2];
  const float* Wout = (const float*)d_in[3];
  float* outp = (float*)d_out;

  // Workspace layout (~83.5 MB total; all offsets 16B-aligned)
  char* ws = (char*)d_ws;
  size_t off = 0;
  u16* xt   = (u16*)(ws + off); off += (size_t)B_ * D_ * N_ * 2;          // 25.2 MB
  u16* qkb  = (u16*)(ws + off); off += (size_t)B_ * H_ * D_ * QROW * 2;   // 26.2 MB
  u16* vtb  = (u16*)(ws + off); off += (size_t)B_ * H_ * 32 * HN * VROW * 2; // 28.3 MB
  float* q2 = (float*)(ws + off); off += (size_t)B_ * H_ * D_ * 4;        // 256 KB
  u16* wqk_bf  = (u16*)(ws + off); off += (size_t)N_ * N_ * 2;
  u16* wv_bf   = (u16*)(ws + off); off += (size_t)N_ * N_ * 2;
  u16* wout_bf = (u16*)(ws + off); off += (size_t)N_ * N_ * 2;
  u16* wbuf = xt;   // xt dead after the qk/v GEMMs; reuse for attention output

  prep<<<dim3(4864), 256, 0, stream>>>(x, Wqk, Wv, Wout, xt, wqk_bf, wv_bf, wout_bf, q2);
  qk_gemm<<<dim3(D_ / 256, H_, B_), 512, 0, stream>>>(xt, wqk_bf, qkb, q2);
  v_gemm<<<dim3(D_ / 256, H_, B_), 512, 0, stream>>>(xt, wv_bf, vtb);
  attn_kernel<<<dim3((D_ / 128) * B_ * H_), 256, 0, stream>>>(qkb, vtb, q2, wbuf);
  out_gemm<<<dim3(D_ / 256, N_ / 192, B_), 512, 0, stream>>>(wbuf, wout_bf, outp);
}